// Round 2
// baseline (428.568 us; speedup 1.0000x reference)
//
#include <hip/hip_runtime.h>
#include <hip/hip_bf16.h>

// Problem constants
#define B_    8
#define NT_   8192
#define NS_   2048
#define NTOT  (B_ * NT_)    // 65536 target points
#define CTGT  128
#define CSRC  256
#define CIN   384           // CTGT + CSRC
#define CHID  256
#define COUT  128

typedef __bf16 bf16x8 __attribute__((ext_vector_type(8)));
typedef float  f32x4  __attribute__((ext_vector_type(4)));
typedef unsigned short u16x8 __attribute__((ext_vector_type(8)));

__device__ inline unsigned short f2bf(float f) {
    unsigned int u = __float_as_uint(f);
    u += 0x7FFF + ((u >> 16) & 1);   // round-to-nearest-even
    return (unsigned short)(u >> 16);
}

// ---------------------------------------------------------------------------
// K0: build bf16 transposed weight matrices in workspace.
// Wc_t [384][384]: row n (n<256 -> W1 col n, else Ws col n-256), col k.
// W2_t [128][256]: row n, col k.
// ---------------------------------------------------------------------------
__global__ __launch_bounds__(256) void prep_weights(
    const float* __restrict__ W1, const float* __restrict__ Ws,
    const float* __restrict__ W2,
    unsigned short* __restrict__ Wct, unsigned short* __restrict__ W2t) {
    int g = blockIdx.x * 256 + threadIdx.x;
    if (g < CIN * CIN) {
        int n = g / CIN, k = g % CIN;
        float v = (n < CHID) ? W1[(size_t)k * CHID + n]
                             : Ws[(size_t)k * COUT + (n - CHID)];
        Wct[g] = f2bf(v);
    } else {
        int g2 = g - CIN * CIN;
        if (g2 < COUT * CHID) {
            int n = g2 / CHID, k = g2 % CHID;
            W2t[g2] = f2bf(W2[(size_t)k * COUT + n]);
        }
    }
}

// ---------------------------------------------------------------------------
// K1: brute-force KNN (top-3 smallest squared distance) per target point.
// One block = 256 consecutive targets (same batch). Source positions in LDS.
// fp32 arithmetic with explicit mul/add (no FMA) to bit-match numpy d2.
// ---------------------------------------------------------------------------
__global__ __launch_bounds__(256) void knn_kernel(
    const float* __restrict__ pos_t, const float* __restrict__ pos_s,
    int* __restrict__ knn_i, float* __restrict__ knn_d) {
    __shared__ float ps[NS_ * 3];
    int b = blockIdx.x;              // 256 blocks
    int batch = b >> 5;              // 32 blocks per batch
    const float* src = pos_s + (size_t)batch * NS_ * 3;
    for (int i = threadIdx.x; i < NS_ * 3; i += 256) ps[i] = src[i];
    __syncthreads();

    int t = b * 256 + threadIdx.x;
    float ptx = pos_t[t * 3 + 0];
    float pty = pos_t[t * 3 + 1];
    float ptz = pos_t[t * 3 + 2];

    float d0 = 3.4e38f, d1 = 3.4e38f, d2v = 3.4e38f;
    int i0 = 0, i1 = 0, i2 = 0;
    for (int j = 0; j < NS_; ++j) {
        float dx = __fsub_rn(ptx, ps[j * 3 + 0]);
        float dy = __fsub_rn(pty, ps[j * 3 + 1]);
        float dz = __fsub_rn(ptz, ps[j * 3 + 2]);
        float d = __fadd_rn(__fadd_rn(__fmul_rn(dx, dx), __fmul_rn(dy, dy)),
                            __fmul_rn(dz, dz));
        if (d < d2v) {
            if (d < d1) {
                d2v = d1; i2 = i1;
                if (d < d0) { d1 = d0; i1 = i0; d0 = d; i0 = j; }
                else        { d1 = d;  i1 = j; }
            } else { d2v = d; i2 = j; }
        }
    }
    knn_i[t * 3 + 0] = i0; knn_i[t * 3 + 1] = i1; knn_i[t * 3 + 2] = i2;
    knn_d[t * 3 + 0] = d0; knn_d[t * 3 + 1] = d1; knn_d[t * 3 + 2] = d2v;
}

// ---------------------------------------------------------------------------
// K2: interpolate + concat -> combined bf16 [NTOT][384].
// Thread handles 4 contiguous channels. seg<32: copy x_target; else gather.
// ---------------------------------------------------------------------------
__global__ __launch_bounds__(256) void interp_kernel(
    const float* __restrict__ x_t, const float* __restrict__ x_s,
    const int* __restrict__ knn_i, const float* __restrict__ knn_d,
    unsigned short* __restrict__ combined) {
    int g = blockIdx.x * 256 + threadIdx.x;   // NTOT*96 threads
    int row = g / 96, seg = g % 96;
    if (row >= NTOT) return;
    if (seg < 32) {
        float4 v = *(const float4*)(x_t + (size_t)row * CTGT + seg * 4);
        ushort4 o;
        o.x = f2bf(v.x); o.y = f2bf(v.y); o.z = f2bf(v.z); o.w = f2bf(v.w);
        *(ushort4*)(combined + (size_t)row * CIN + seg * 4) = o;
    } else {
        int c = (seg - 32) * 4;
        int batch = row >> 13;   // row / 8192
        const float* xsb = x_s + (size_t)batch * NS_ * CSRC;
        int i0 = knn_i[row * 3 + 0];
        int i1 = knn_i[row * 3 + 1];
        int i2 = knn_i[row * 3 + 2];
        float w0 = 1.0f / fmaxf(knn_d[row * 3 + 0], 1e-16f);
        float w1 = 1.0f / fmaxf(knn_d[row * 3 + 1], 1e-16f);
        float w2 = 1.0f / fmaxf(knn_d[row * 3 + 2], 1e-16f);
        float inv = 1.0f / (w0 + w1 + w2);
        float4 a = *(const float4*)(xsb + (size_t)i0 * CSRC + c);
        float4 b = *(const float4*)(xsb + (size_t)i1 * CSRC + c);
        float4 d = *(const float4*)(xsb + (size_t)i2 * CSRC + c);
        ushort4 o;
        o.x = f2bf((w0 * a.x + w1 * b.x + w2 * d.x) * inv);
        o.y = f2bf((w0 * a.y + w1 * b.y + w2 * d.y) * inv);
        o.z = f2bf((w0 * a.z + w1 * b.z + w2 * d.z) * inv);
        o.w = f2bf((w0 * a.w + w1 * b.w + w2 * d.w) * inv);
        *(ushort4*)(combined + (size_t)row * CIN + CTGT + c) = o;
    }
}

// ---------------------------------------------------------------------------
// K3: GEMM1  combined[65536x384](bf16) @ Wc[384x384] -> split epilogue:
//   n<256 : relu(acc + b1[n])  -> hbuf bf16 [M][256]
//   n>=256: acc + bs[n-256]    -> resbuf f32 [M][128]
// 128x128 tile, 4 waves (2x2), 16x16x32 bf16 MFMA, BK=32, LDS pad +8.
// ---------------------------------------------------------------------------
__global__ __launch_bounds__(256) void gemm1_kernel(
    const unsigned short* __restrict__ A, const unsigned short* __restrict__ Bt,
    const float* __restrict__ b1, const float* __restrict__ bs,
    unsigned short* __restrict__ hbuf, float* __restrict__ resbuf) {
    __shared__ unsigned short Alds[128 * 40];
    __shared__ unsigned short Blds[128 * 40];
    int bm = blockIdx.x;         // 512
    int bn = blockIdx.y;         // 3
    int tid = threadIdx.x;
    int wid = tid >> 6, lane = tid & 63;
    int wm = wid >> 1, wn = wid & 1;
    int lrow = lane & 15;
    int kgrp = (lane >> 4) * 8;

    f32x4 acc[4][4] = {};

    for (int k0 = 0; k0 < CIN; k0 += 32) {
#pragma unroll
        for (int i = 0; i < 2; ++i) {
            int c = tid + i * 256;
            int row = c >> 2, kk = (c & 3) * 8;
            u16x8 va = *(const u16x8*)(A + (size_t)(bm * 128 + row) * CIN + k0 + kk);
            *(u16x8*)(&Alds[row * 40 + kk]) = va;
            u16x8 vb = *(const u16x8*)(Bt + (size_t)(bn * 128 + row) * CIN + k0 + kk);
            *(u16x8*)(&Blds[row * 40 + kk]) = vb;
        }
        __syncthreads();
        bf16x8 af[4], bf[4];
#pragma unroll
        for (int mi = 0; mi < 4; ++mi)
            af[mi] = *(const bf16x8*)(&Alds[(wm * 64 + mi * 16 + lrow) * 40 + kgrp]);
#pragma unroll
        for (int ni = 0; ni < 4; ++ni)
            bf[ni] = *(const bf16x8*)(&Blds[(wn * 64 + ni * 16 + lrow) * 40 + kgrp]);
#pragma unroll
        for (int mi = 0; mi < 4; ++mi)
#pragma unroll
            for (int ni = 0; ni < 4; ++ni)
                acc[mi][ni] = __builtin_amdgcn_mfma_f32_16x16x32_bf16(
                    af[mi], bf[ni], acc[mi][ni], 0, 0, 0);
        __syncthreads();
    }

    int r0 = (lane >> 4) * 4;
#pragma unroll
    for (int mi = 0; mi < 4; ++mi)
#pragma unroll
        for (int ni = 0; ni < 4; ++ni) {
            int n = bn * 128 + wn * 64 + ni * 16 + lrow;
#pragma unroll
            for (int r = 0; r < 4; ++r) {
                int m = bm * 128 + wm * 64 + mi * 16 + r0 + r;
                float v = acc[mi][ni][r];
                if (n < CHID) {
                    v += b1[n];
                    v = fmaxf(v, 0.0f);
                    hbuf[(size_t)m * CHID + n] = f2bf(v);
                } else {
                    int n2 = n - CHID;
                    resbuf[(size_t)m * COUT + n2] = v + bs[n2];
                }
            }
        }
}

// ---------------------------------------------------------------------------
// K4: GEMM2  hbuf[65536x256](bf16) @ W2[256x128] + b2 + resbuf -> relu -> out
// ---------------------------------------------------------------------------
__global__ __launch_bounds__(256) void gemm2_kernel(
    const unsigned short* __restrict__ A, const unsigned short* __restrict__ Bt,
    const float* __restrict__ b2, const float* __restrict__ resbuf,
    float* __restrict__ out) {
    __shared__ unsigned short Alds[128 * 40];
    __shared__ unsigned short Blds[128 * 40];
    int bm = blockIdx.x;         // 512
    int tid = threadIdx.x;
    int wid = tid >> 6, lane = tid & 63;
    int wm = wid >> 1, wn = wid & 1;
    int lrow = lane & 15;
    int kgrp = (lane >> 4) * 8;

    f32x4 acc[4][4] = {};

    for (int k0 = 0; k0 < CHID; k0 += 32) {
#pragma unroll
        for (int i = 0; i < 2; ++i) {
            int c = tid + i * 256;
            int row = c >> 2, kk = (c & 3) * 8;
            u16x8 va = *(const u16x8*)(A + (size_t)(bm * 128 + row) * CHID + k0 + kk);
            *(u16x8*)(&Alds[row * 40 + kk]) = va;
            u16x8 vb = *(const u16x8*)(Bt + (size_t)row * CHID + k0 + kk);
            *(u16x8*)(&Blds[row * 40 + kk]) = vb;
        }
        __syncthreads();
        bf16x8 af[4], bf[4];
#pragma unroll
        for (int mi = 0; mi < 4; ++mi)
            af[mi] = *(const bf16x8*)(&Alds[(wm * 64 + mi * 16 + lrow) * 40 + kgrp]);
#pragma unroll
        for (int ni = 0; ni < 4; ++ni)
            bf[ni] = *(const bf16x8*)(&Blds[(wn * 64 + ni * 16 + lrow) * 40 + kgrp]);
#pragma unroll
        for (int mi = 0; mi < 4; ++mi)
#pragma unroll
            for (int ni = 0; ni < 4; ++ni)
                acc[mi][ni] = __builtin_amdgcn_mfma_f32_16x16x32_bf16(
                    af[mi], bf[ni], acc[mi][ni], 0, 0, 0);
        __syncthreads();
    }

    int r0 = (lane >> 4) * 4;
#pragma unroll
    for (int mi = 0; mi < 4; ++mi)
#pragma unroll
        for (int ni = 0; ni < 4; ++ni) {
            int n = wn * 64 + ni * 16 + lrow;   // 0..127
#pragma unroll
            for (int r = 0; r < 4; ++r) {
                int m = bm * 128 + wm * 64 + mi * 16 + r0 + r;
                float v = acc[mi][ni][r] + b2[n] + resbuf[(size_t)m * COUT + n];
                out[(size_t)m * COUT + n] = fmaxf(v, 0.0f);
            }
        }
}

// ---------------------------------------------------------------------------
extern "C" void kernel_launch(void* const* d_in, const int* in_sizes, int n_in,
                              void* d_out, int out_size, void* d_ws, size_t ws_size,
                              hipStream_t stream) {
    const float* x_t   = (const float*)d_in[0];
    const float* pos_t = (const float*)d_in[1];
    const float* x_s   = (const float*)d_in[3];
    const float* pos_s = (const float*)d_in[4];
    const float* W1    = (const float*)d_in[6];
    const float* b1    = (const float*)d_in[7];
    const float* W2    = (const float*)d_in[8];
    const float* b2    = (const float*)d_in[9];
    const float* Ws    = (const float*)d_in[10];
    const float* bs    = (const float*)d_in[11];

    char* ws = (char*)d_ws;
    // workspace layout (bytes)
    int*            knn_i  = (int*)           (ws + 0);           //  786,432
    float*          knn_d  = (float*)         (ws + 786432);      //  786,432
    unsigned short* Wct    = (unsigned short*)(ws + 1572864);     //  294,912
    unsigned short* W2t    = (unsigned short*)(ws + 1867776);     //   65,536
    unsigned short* comb   = (unsigned short*)(ws + 1933312);     // 50,331,648
    unsigned short* hbuf   = (unsigned short*)(ws + 52264960);    // 33,554,432
    float*          resbuf = (float*)         (ws + 85819392);    // 33,554,432
    float*          out    = (float*)d_out;

    prep_weights<<<704, 256, 0, stream>>>(W1, Ws, W2, Wct, W2t);
    knn_kernel<<<NTOT / 256, 256, 0, stream>>>(pos_t, pos_s, knn_i, knn_d);
    interp_kernel<<<(NTOT * 96) / 256, 256, 0, stream>>>(x_t, x_s, knn_i, knn_d, comb);
    dim3 g1(NTOT / 128, CIN / 128);
    gemm1_kernel<<<g1, 256, 0, stream>>>(comb, Wct, b1, bs, hbuf, resbuf);
    gemm2_kernel<<<NTOT / 128, 256, 0, stream>>>(hbuf, W2t, b2, resbuf, out);
}

// Round 3
// 304.424 us; speedup vs baseline: 1.4078x; 1.4078x over previous
//
#include <hip/hip_runtime.h>
#include <hip/hip_bf16.h>

// Problem constants
#define B_    8
#define NT_   8192
#define NS_   2048
#define NTOT  (B_ * NT_)    // 65536 target points
#define CTGT  128
#define CSRC  256
#define CIN   384           // CTGT + CSRC
#define CHID  256
#define COUT  128

typedef __bf16 bf16x8 __attribute__((ext_vector_type(8)));
typedef float  f32x4  __attribute__((ext_vector_type(4)));
typedef unsigned short u16x8 __attribute__((ext_vector_type(8)));

__device__ inline unsigned short f2bf(float f) {
    unsigned int u = __float_as_uint(f);
    u += 0x7FFF + ((u >> 16) & 1);   // round-to-nearest-even
    return (unsigned short)(u >> 16);
}

// ---------------------------------------------------------------------------
// K0: build bf16 transposed weight matrices in workspace.
// ---------------------------------------------------------------------------
__global__ __launch_bounds__(256) void prep_weights(
    const float* __restrict__ W1, const float* __restrict__ Ws,
    const float* __restrict__ W2,
    unsigned short* __restrict__ Wct, unsigned short* __restrict__ W2t) {
    int g = blockIdx.x * 256 + threadIdx.x;
    if (g < CIN * CIN) {
        int n = g / CIN, k = g % CIN;
        float v = (n < CHID) ? W1[(size_t)k * CHID + n]
                             : Ws[(size_t)k * COUT + (n - CHID)];
        Wct[g] = f2bf(v);
    } else {
        int g2 = g - CIN * CIN;
        if (g2 < COUT * CHID) {
            int n = g2 / CHID, k = g2 % CHID;
            W2t[g2] = f2bf(W2[(size_t)k * COUT + n]);
        }
    }
}

// ---------------------------------------------------------------------------
// K1: brute-force KNN, parallelized.
// Block = 256 threads = 32 targets x 8 source-chunks (256 sources each).
// Grid = 2048 blocks (256 per batch) -> 4 blocks/CU (LDS-capped), 16 waves/CU.
// Source positions in LDS as float4 -> one broadcast ds_read_b128 per source.
// fp32 arithmetic with explicit mul/add (no FMA) to bit-match numpy d2;
// chunk-ordered merge with strict < preserves lowest-index tie-break.
// ---------------------------------------------------------------------------
__global__ __launch_bounds__(256) void knn_kernel(
    const float* __restrict__ pos_t, const float* __restrict__ pos_s,
    int* __restrict__ knn_i, float* __restrict__ knn_d) {
    __shared__ float4 ps4[NS_];          // 32 KB
    __shared__ float  md[256 * 3];       // partial top-3 distances
    __shared__ int    mi[256 * 3];       // partial top-3 indices

    int blk = blockIdx.x;                // 2048 blocks
    int batch = blk >> 8;                // 256 blocks per batch
    const float* src = pos_s + (size_t)batch * NS_ * 3;
    for (int i = threadIdx.x; i < NS_; i += 256) {
        ps4[i] = make_float4(src[i * 3 + 0], src[i * 3 + 1], src[i * 3 + 2], 0.0f);
    }
    __syncthreads();

    int tl = threadIdx.x & 31;           // target lane within block
    int ck = threadIdx.x >> 5;           // source chunk 0..7
    int t = blk * 32 + tl;
    float ptx = pos_t[t * 3 + 0];
    float pty = pos_t[t * 3 + 1];
    float ptz = pos_t[t * 3 + 2];

    float d0 = 3.4e38f, d1 = 3.4e38f, d2v = 3.4e38f;
    int i0 = 0, i1 = 0, i2 = 0;
    int jbeg = ck * 256, jend = jbeg + 256;
#pragma unroll 4
    for (int j = jbeg; j < jend; ++j) {
        float4 p = ps4[j];
        float dx = __fsub_rn(ptx, p.x);
        float dy = __fsub_rn(pty, p.y);
        float dz = __fsub_rn(ptz, p.z);
        float d = __fadd_rn(__fadd_rn(__fmul_rn(dx, dx), __fmul_rn(dy, dy)),
                            __fmul_rn(dz, dz));
        if (d < d2v) {
            if (d < d1) {
                d2v = d1; i2 = i1;
                if (d < d0) { d1 = d0; i1 = i0; d0 = d; i0 = j; }
                else        { d1 = d;  i1 = j; }
            } else { d2v = d; i2 = j; }
        }
    }
    int slot = (tl * 8 + ck) * 3;
    md[slot + 0] = d0;  md[slot + 1] = d1;  md[slot + 2] = d2v;
    mi[slot + 0] = i0;  mi[slot + 1] = i1;  mi[slot + 2] = i2;
    __syncthreads();

    if (ck == 0) {
        // merge 8 chunk-partials in chunk order (ascending source index),
        // strict < keeps the earlier (lower-index) candidate on ties.
        float e0 = md[tl * 24 + 0], e1 = md[tl * 24 + 1], e2 = md[tl * 24 + 2];
        int   j0 = mi[tl * 24 + 0], j1 = mi[tl * 24 + 1], j2 = mi[tl * 24 + 2];
#pragma unroll
        for (int c = 1; c < 8; ++c) {
#pragma unroll
            for (int r = 0; r < 3; ++r) {
                float d = md[tl * 24 + c * 3 + r];
                int   i = mi[tl * 24 + c * 3 + r];
                if (d < e2) {
                    if (d < e1) {
                        e2 = e1; j2 = j1;
                        if (d < e0) { e1 = e0; j1 = j0; e0 = d; j0 = i; }
                        else        { e1 = d;  j1 = i; }
                    } else { e2 = d; j2 = i; }
                }
            }
        }
        knn_i[t * 3 + 0] = j0; knn_i[t * 3 + 1] = j1; knn_i[t * 3 + 2] = j2;
        knn_d[t * 3 + 0] = e0; knn_d[t * 3 + 1] = e1; knn_d[t * 3 + 2] = e2;
    }
}

// ---------------------------------------------------------------------------
// K2: interpolate + concat -> combined bf16 [NTOT][384].
// ---------------------------------------------------------------------------
__global__ __launch_bounds__(256) void interp_kernel(
    const float* __restrict__ x_t, const float* __restrict__ x_s,
    const int* __restrict__ knn_i, const float* __restrict__ knn_d,
    unsigned short* __restrict__ combined) {
    int g = blockIdx.x * 256 + threadIdx.x;   // NTOT*96 threads
    int row = g / 96, seg = g % 96;
    if (row >= NTOT) return;
    if (seg < 32) {
        float4 v = *(const float4*)(x_t + (size_t)row * CTGT + seg * 4);
        ushort4 o;
        o.x = f2bf(v.x); o.y = f2bf(v.y); o.z = f2bf(v.z); o.w = f2bf(v.w);
        *(ushort4*)(combined + (size_t)row * CIN + seg * 4) = o;
    } else {
        int c = (seg - 32) * 4;
        int batch = row >> 13;   // row / 8192
        const float* xsb = x_s + (size_t)batch * NS_ * CSRC;
        int i0 = knn_i[row * 3 + 0];
        int i1 = knn_i[row * 3 + 1];
        int i2 = knn_i[row * 3 + 2];
        float w0 = 1.0f / fmaxf(knn_d[row * 3 + 0], 1e-16f);
        float w1 = 1.0f / fmaxf(knn_d[row * 3 + 1], 1e-16f);
        float w2 = 1.0f / fmaxf(knn_d[row * 3 + 2], 1e-16f);
        float inv = 1.0f / (w0 + w1 + w2);
        float4 a = *(const float4*)(xsb + (size_t)i0 * CSRC + c);
        float4 b = *(const float4*)(xsb + (size_t)i1 * CSRC + c);
        float4 d = *(const float4*)(xsb + (size_t)i2 * CSRC + c);
        ushort4 o;
        o.x = f2bf((w0 * a.x + w1 * b.x + w2 * d.x) * inv);
        o.y = f2bf((w0 * a.y + w1 * b.y + w2 * d.y) * inv);
        o.z = f2bf((w0 * a.z + w1 * b.z + w2 * d.z) * inv);
        o.w = f2bf((w0 * a.w + w1 * b.w + w2 * d.w) * inv);
        *(ushort4*)(combined + (size_t)row * CIN + CTGT + c) = o;
    }
}

// ---------------------------------------------------------------------------
// K3: GEMM1  combined[65536x384](bf16) @ Wc[384x384] -> split epilogue:
//   n<256 : relu(acc + b1[n])  -> hbuf bf16 [M][256]
//   n>=256: acc + bs[n-256]    -> resbuf f32 [M][128]
// ---------------------------------------------------------------------------
__global__ __launch_bounds__(256) void gemm1_kernel(
    const unsigned short* __restrict__ A, const unsigned short* __restrict__ Bt,
    const float* __restrict__ b1, const float* __restrict__ bs,
    unsigned short* __restrict__ hbuf, float* __restrict__ resbuf) {
    __shared__ unsigned short Alds[128 * 40];
    __shared__ unsigned short Blds[128 * 40];
    int bm = blockIdx.x;         // 512
    int bn = blockIdx.y;         // 3
    int tid = threadIdx.x;
    int wid = tid >> 6, lane = tid & 63;
    int wm = wid >> 1, wn = wid & 1;
    int lrow = lane & 15;
    int kgrp = (lane >> 4) * 8;

    f32x4 acc[4][4] = {};

    for (int k0 = 0; k0 < CIN; k0 += 32) {
#pragma unroll
        for (int i = 0; i < 2; ++i) {
            int c = tid + i * 256;
            int row = c >> 2, kk = (c & 3) * 8;
            u16x8 va = *(const u16x8*)(A + (size_t)(bm * 128 + row) * CIN + k0 + kk);
            *(u16x8*)(&Alds[row * 40 + kk]) = va;
            u16x8 vb = *(const u16x8*)(Bt + (size_t)(bn * 128 + row) * CIN + k0 + kk);
            *(u16x8*)(&Blds[row * 40 + kk]) = vb;
        }
        __syncthreads();
        bf16x8 af[4], bf[4];
#pragma unroll
        for (int mi = 0; mi < 4; ++mi)
            af[mi] = *(const bf16x8*)(&Alds[(wm * 64 + mi * 16 + lrow) * 40 + kgrp]);
#pragma unroll
        for (int ni = 0; ni < 4; ++ni)
            bf[ni] = *(const bf16x8*)(&Blds[(wn * 64 + ni * 16 + lrow) * 40 + kgrp]);
#pragma unroll
        for (int mi = 0; mi < 4; ++mi)
#pragma unroll
            for (int ni = 0; ni < 4; ++ni)
                acc[mi][ni] = __builtin_amdgcn_mfma_f32_16x16x32_bf16(
                    af[mi], bf[ni], acc[mi][ni], 0, 0, 0);
        __syncthreads();
    }

    int r0 = (lane >> 4) * 4;
#pragma unroll
    for (int mi = 0; mi < 4; ++mi)
#pragma unroll
        for (int ni = 0; ni < 4; ++ni) {
            int n = bn * 128 + wn * 64 + ni * 16 + lrow;
#pragma unroll
            for (int r = 0; r < 4; ++r) {
                int m = bm * 128 + wm * 64 + mi * 16 + r0 + r;
                float v = acc[mi][ni][r];
                if (n < CHID) {
                    v += b1[n];
                    v = fmaxf(v, 0.0f);
                    hbuf[(size_t)m * CHID + n] = f2bf(v);
                } else {
                    int n2 = n - CHID;
                    resbuf[(size_t)m * COUT + n2] = v + bs[n2];
                }
            }
        }
}

// ---------------------------------------------------------------------------
// K4: GEMM2  hbuf[65536x256](bf16) @ W2[256x128] + b2 + resbuf -> relu -> out
// ---------------------------------------------------------------------------
__global__ __launch_bounds__(256) void gemm2_kernel(
    const unsigned short* __restrict__ A, const unsigned short* __restrict__ Bt,
    const float* __restrict__ b2, const float* __restrict__ resbuf,
    float* __restrict__ out) {
    __shared__ unsigned short Alds[128 * 40];
    __shared__ unsigned short Blds[128 * 40];
    int bm = blockIdx.x;         // 512
    int tid = threadIdx.x;
    int wid = tid >> 6, lane = tid & 63;
    int wm = wid >> 1, wn = wid & 1;
    int lrow = lane & 15;
    int kgrp = (lane >> 4) * 8;

    f32x4 acc[4][4] = {};

    for (int k0 = 0; k0 < CHID; k0 += 32) {
#pragma unroll
        for (int i = 0; i < 2; ++i) {
            int c = tid + i * 256;
            int row = c >> 2, kk = (c & 3) * 8;
            u16x8 va = *(const u16x8*)(A + (size_t)(bm * 128 + row) * CHID + k0 + kk);
            *(u16x8*)(&Alds[row * 40 + kk]) = va;
            u16x8 vb = *(const u16x8*)(Bt + (size_t)row * CHID + k0 + kk);
            *(u16x8*)(&Blds[row * 40 + kk]) = vb;
        }
        __syncthreads();
        bf16x8 af[4], bf[4];
#pragma unroll
        for (int mi = 0; mi < 4; ++mi)
            af[mi] = *(const bf16x8*)(&Alds[(wm * 64 + mi * 16 + lrow) * 40 + kgrp]);
#pragma unroll
        for (int ni = 0; ni < 4; ++ni)
            bf[ni] = *(const bf16x8*)(&Blds[(wn * 64 + ni * 16 + lrow) * 40 + kgrp]);
#pragma unroll
        for (int mi = 0; mi < 4; ++mi)
#pragma unroll
            for (int ni = 0; ni < 4; ++ni)
                acc[mi][ni] = __builtin_amdgcn_mfma_f32_16x16x32_bf16(
                    af[mi], bf[ni], acc[mi][ni], 0, 0, 0);
        __syncthreads();
    }

    int r0 = (lane >> 4) * 4;
#pragma unroll
    for (int mi = 0; mi < 4; ++mi)
#pragma unroll
        for (int ni = 0; ni < 4; ++ni) {
            int n = wn * 64 + ni * 16 + lrow;   // 0..127
#pragma unroll
            for (int r = 0; r < 4; ++r) {
                int m = bm * 128 + wm * 64 + mi * 16 + r0 + r;
                float v = acc[mi][ni][r] + b2[n] + resbuf[(size_t)m * COUT + n];
                out[(size_t)m * COUT + n] = fmaxf(v, 0.0f);
            }
        }
}

// ---------------------------------------------------------------------------
extern "C" void kernel_launch(void* const* d_in, const int* in_sizes, int n_in,
                              void* d_out, int out_size, void* d_ws, size_t ws_size,
                              hipStream_t stream) {
    const float* x_t   = (const float*)d_in[0];
    const float* pos_t = (const float*)d_in[1];
    const float* x_s   = (const float*)d_in[3];
    const float* pos_s = (const float*)d_in[4];
    const float* W1    = (const float*)d_in[6];
    const float* b1    = (const float*)d_in[7];
    const float* W2    = (const float*)d_in[8];
    const float* b2    = (const float*)d_in[9];
    const float* Ws    = (const float*)d_in[10];
    const float* bs    = (const float*)d_in[11];

    char* ws = (char*)d_ws;
    // workspace layout (bytes)
    int*            knn_i  = (int*)           (ws + 0);           //  786,432
    float*          knn_d  = (float*)         (ws + 786432);      //  786,432
    unsigned short* Wct    = (unsigned short*)(ws + 1572864);     //  294,912
    unsigned short* W2t    = (unsigned short*)(ws + 1867776);     //   65,536
    unsigned short* comb   = (unsigned short*)(ws + 1933312);     // 50,331,648
    unsigned short* hbuf   = (unsigned short*)(ws + 52264960);    // 33,554,432
    float*          resbuf = (float*)         (ws + 85819392);    // 33,554,432
    float*          out    = (float*)d_out;

    prep_weights<<<704, 256, 0, stream>>>(W1, Ws, W2, Wct, W2t);
    knn_kernel<<<NTOT / 32, 256, 0, stream>>>(pos_t, pos_s, knn_i, knn_d);
    interp_kernel<<<(NTOT * 96) / 256, 256, 0, stream>>>(x_t, x_s, knn_i, knn_d, comb);
    dim3 g1(NTOT / 128, CIN / 128);
    gemm1_kernel<<<g1, 256, 0, stream>>>(comb, Wct, b1, bs, hbuf, resbuf);
    gemm2_kernel<<<NTOT / 128, 256, 0, stream>>>(hbuf, W2t, b2, resbuf, out);
}

// Round 5
// 275.000 us; speedup vs baseline: 1.5584x; 1.1070x over previous
//
#include <hip/hip_runtime.h>
#include <hip/hip_bf16.h>

// Problem constants
#define B_    8
#define NT_   8192
#define NS_   2048
#define NTOT  (B_ * NT_)    // 65536 target points
#define CTGT  128
#define CSRC  256
#define CIN   384           // CTGT + CSRC
#define CHID  256
#define COUT  128

typedef __bf16 bf16x8 __attribute__((ext_vector_type(8)));
typedef float  f32x4  __attribute__((ext_vector_type(4)));
typedef unsigned short u16x8 __attribute__((ext_vector_type(8)));

__device__ inline unsigned short f2bf(float f) {
    unsigned int u = __float_as_uint(f);
    u += 0x7FFF + ((u >> 16) & 1);   // round-to-nearest-even
    return (unsigned short)(u >> 16);
}

// async global->LDS, 16B per lane, dest = wave-uniform base + lane*16
__device__ __forceinline__ void gload16(const unsigned short* g, unsigned short* l) {
    __builtin_amdgcn_global_load_lds(
        (const __attribute__((address_space(1))) unsigned int*)g,
        (__attribute__((address_space(3))) unsigned int*)l, 16, 0, 0);
}

// ---------------------------------------------------------------------------
// Shared GEMM staging: tile is [128 rows][32 cols] bf16, linear LDS (8KB).
// Swizzle (both-sides, rule #21): LDS[row][col] holds G[row][col ^ swz(row)],
// swz(row) = ((row>>1)&3)*8 elements. Staged via pre-swizzled global SOURCE
// (gload_lds dest must be linear); fragment reads apply the same XOR.
// 16 lanes per k-group then hit 8 distinct 4-bank slots -> 2-way = free.
// ---------------------------------------------------------------------------
__device__ __forceinline__ void stage_ab(
    const unsigned short* __restrict__ ga, int ldA,
    const unsigned short* __restrict__ gb, int ldB,
    unsigned short* Alds, unsigned short* Blds,
    int k0, int widu, int lane) {
    int rloc = lane >> 2;                              // row within 16-row chunk
    int cswz = ((lane & 3) ^ ((lane >> 3) & 3)) * 8;   // pre-swizzled src col (elems)
#pragma unroll
    for (int i = 0; i < 2; ++i) {
        int c = widu * 2 + i;                          // chunk 0..7 (16 rows each)
        int row = c * 16 + rloc;
        gload16(ga + (size_t)row * ldA + k0 + cswz, Alds + c * 512);
        gload16(gb + (size_t)row * ldB + k0 + cswz, Blds + c * 512);
    }
}

// ---------------------------------------------------------------------------
// K0: build bf16 transposed weight matrices in workspace.
// ---------------------------------------------------------------------------
__global__ __launch_bounds__(256) void prep_weights(
    const float* __restrict__ W1, const float* __restrict__ Ws,
    const float* __restrict__ W2,
    unsigned short* __restrict__ Wct, unsigned short* __restrict__ W2t) {
    int g = blockIdx.x * 256 + threadIdx.x;
    if (g < CIN * CIN) {
        int n = g / CIN, k = g % CIN;
        float v = (n < CHID) ? W1[(size_t)k * CHID + n]
                             : Ws[(size_t)k * COUT + (n - CHID)];
        Wct[g] = f2bf(v);
    } else {
        int g2 = g - CIN * CIN;
        if (g2 < COUT * CHID) {
            int n = g2 / CHID, k = g2 % CHID;
            W2t[g2] = f2bf(W2[(size_t)k * COUT + n]);
        }
    }
}

// ---------------------------------------------------------------------------
// K1: brute-force KNN, parallelized (unchanged from validated round 3).
// ---------------------------------------------------------------------------
__global__ __launch_bounds__(256) void knn_kernel(
    const float* __restrict__ pos_t, const float* __restrict__ pos_s,
    int* __restrict__ knn_i, float* __restrict__ knn_d) {
    __shared__ float4 ps4[NS_];          // 32 KB
    __shared__ float  md[256 * 3];
    __shared__ int    mi[256 * 3];

    int blk = blockIdx.x;                // 2048 blocks
    int batch = blk >> 8;
    const float* src = pos_s + (size_t)batch * NS_ * 3;
    for (int i = threadIdx.x; i < NS_; i += 256) {
        ps4[i] = make_float4(src[i * 3 + 0], src[i * 3 + 1], src[i * 3 + 2], 0.0f);
    }
    __syncthreads();

    int tl = threadIdx.x & 31;
    int ck = threadIdx.x >> 5;
    int t = blk * 32 + tl;
    float ptx = pos_t[t * 3 + 0];
    float pty = pos_t[t * 3 + 1];
    float ptz = pos_t[t * 3 + 2];

    float d0 = 3.4e38f, d1 = 3.4e38f, d2v = 3.4e38f;
    int i0 = 0, i1 = 0, i2 = 0;
    int jbeg = ck * 256, jend = jbeg + 256;
#pragma unroll 4
    for (int j = jbeg; j < jend; ++j) {
        float4 p = ps4[j];
        float dx = __fsub_rn(ptx, p.x);
        float dy = __fsub_rn(pty, p.y);
        float dz = __fsub_rn(ptz, p.z);
        float d = __fadd_rn(__fadd_rn(__fmul_rn(dx, dx), __fmul_rn(dy, dy)),
                            __fmul_rn(dz, dz));
        if (d < d2v) {
            if (d < d1) {
                d2v = d1; i2 = i1;
                if (d < d0) { d1 = d0; i1 = i0; d0 = d; i0 = j; }
                else        { d1 = d;  i1 = j; }
            } else { d2v = d; i2 = j; }
        }
    }
    int slot = (tl * 8 + ck) * 3;
    md[slot + 0] = d0;  md[slot + 1] = d1;  md[slot + 2] = d2v;
    mi[slot + 0] = i0;  mi[slot + 1] = i1;  mi[slot + 2] = i2;
    __syncthreads();

    if (ck == 0) {
        float e0 = md[tl * 24 + 0], e1 = md[tl * 24 + 1], e2 = md[tl * 24 + 2];
        int   j0 = mi[tl * 24 + 0], j1 = mi[tl * 24 + 1], j2 = mi[tl * 24 + 2];
#pragma unroll
        for (int c = 1; c < 8; ++c) {
#pragma unroll
            for (int r = 0; r < 3; ++r) {
                float d = md[tl * 24 + c * 3 + r];
                int   i = mi[tl * 24 + c * 3 + r];
                if (d < e2) {
                    if (d < e1) {
                        e2 = e1; j2 = j1;
                        if (d < e0) { e1 = e0; j1 = j0; e0 = d; j0 = i; }
                        else        { e1 = d;  j1 = i; }
                    } else { e2 = d; j2 = i; }
                }
            }
        }
        knn_i[t * 3 + 0] = j0; knn_i[t * 3 + 1] = j1; knn_i[t * 3 + 2] = j2;
        knn_d[t * 3 + 0] = e0; knn_d[t * 3 + 1] = e1; knn_d[t * 3 + 2] = e2;
    }
}

// ---------------------------------------------------------------------------
// K2: interpolate + concat -> combined bf16 [NTOT][384]  (unchanged).
// ---------------------------------------------------------------------------
__global__ __launch_bounds__(256) void interp_kernel(
    const float* __restrict__ x_t, const float* __restrict__ x_s,
    const int* __restrict__ knn_i, const float* __restrict__ knn_d,
    unsigned short* __restrict__ combined) {
    int g = blockIdx.x * 256 + threadIdx.x;
    int row = g / 96, seg = g % 96;
    if (row >= NTOT) return;
    if (seg < 32) {
        float4 v = *(const float4*)(x_t + (size_t)row * CTGT + seg * 4);
        ushort4 o;
        o.x = f2bf(v.x); o.y = f2bf(v.y); o.z = f2bf(v.z); o.w = f2bf(v.w);
        *(ushort4*)(combined + (size_t)row * CIN + seg * 4) = o;
    } else {
        int c = (seg - 32) * 4;
        int batch = row >> 13;
        const float* xsb = x_s + (size_t)batch * NS_ * CSRC;
        int i0 = knn_i[row * 3 + 0];
        int i1 = knn_i[row * 3 + 1];
        int i2 = knn_i[row * 3 + 2];
        float w0 = 1.0f / fmaxf(knn_d[row * 3 + 0], 1e-16f);
        float w1 = 1.0f / fmaxf(knn_d[row * 3 + 1], 1e-16f);
        float w2 = 1.0f / fmaxf(knn_d[row * 3 + 2], 1e-16f);
        float inv = 1.0f / (w0 + w1 + w2);
        float4 a = *(const float4*)(xsb + (size_t)i0 * CSRC + c);
        float4 b = *(const float4*)(xsb + (size_t)i1 * CSRC + c);
        float4 d = *(const float4*)(xsb + (size_t)i2 * CSRC + c);
        ushort4 o;
        o.x = f2bf((w0 * a.x + w1 * b.x + w2 * d.x) * inv);
        o.y = f2bf((w0 * a.y + w1 * b.y + w2 * d.y) * inv);
        o.z = f2bf((w0 * a.z + w1 * b.z + w2 * d.z) * inv);
        o.w = f2bf((w0 * a.w + w1 * b.w + w2 * d.w) * inv);
        *(ushort4*)(combined + (size_t)row * CIN + CTGT + c) = o;
    }
}

// ---------------------------------------------------------------------------
// K3: GEMM1  combined[65536x384](bf16) @ Wc[384x384], m97-style pipeline:
// global_load_lds staging, double-buffered prefetch, one barrier per K-step,
// swizzled conflict-free LDS. Split epilogue (relu->hbuf / +bs->resbuf).
// ---------------------------------------------------------------------------
__global__ __launch_bounds__(256) void gemm1_kernel(
    const unsigned short* __restrict__ A, const unsigned short* __restrict__ Bt,
    const float* __restrict__ b1, const float* __restrict__ bs,
    unsigned short* __restrict__ hbuf, float* __restrict__ resbuf) {
    __shared__ unsigned short Alds[2][128 * 32];
    __shared__ unsigned short Blds[2][128 * 32];
    int tid = threadIdx.x;
    int wid = tid >> 6, lane = tid & 63;
    int widu = __builtin_amdgcn_readfirstlane(wid);
    int wm = wid >> 1, wn = wid & 1;
    int r = lane & 15, g = lane >> 4;
    int kcol = (g * 8) ^ (((r >> 1) & 3) * 8);   // swizzled frag column (elems)

    const unsigned short* ga = A  + (size_t)(blockIdx.x * 128) * CIN;
    const unsigned short* gb = Bt + (size_t)(blockIdx.y * 128) * CIN;

    f32x4 acc[4][4] = {};

    stage_ab(ga, CIN, gb, CIN, Alds[0], Blds[0], 0, widu, lane);
    __syncthreads();
    int cur = 0;
#pragma unroll 1
    for (int t = 0; t < 12; ++t) {
        if (t + 1 < 12)
            stage_ab(ga, CIN, gb, CIN, Alds[cur ^ 1], Blds[cur ^ 1],
                     (t + 1) * 32, widu, lane);
        bf16x8 af[4], bf[4];
#pragma unroll
        for (int mi = 0; mi < 4; ++mi)
            af[mi] = *(const bf16x8*)(&Alds[cur][(wm * 64 + mi * 16 + r) * 32 + kcol]);
#pragma unroll
        for (int ni = 0; ni < 4; ++ni)
            bf[ni] = *(const bf16x8*)(&Blds[cur][(wn * 64 + ni * 16 + r) * 32 + kcol]);
#pragma unroll
        for (int mi = 0; mi < 4; ++mi)
#pragma unroll
            for (int ni = 0; ni < 4; ++ni)
                acc[mi][ni] = __builtin_amdgcn_mfma_f32_16x16x32_bf16(
                    af[mi], bf[ni], acc[mi][ni], 0, 0, 0);
        __syncthreads();   // drains prefetch vmcnt; frees buf[cur] for overwrite
        cur ^= 1;
    }

    int r0 = g * 4;
#pragma unroll
    for (int mi = 0; mi < 4; ++mi)
#pragma unroll
        for (int ni = 0; ni < 4; ++ni) {
            int n = blockIdx.y * 128 + wn * 64 + ni * 16 + r;
#pragma unroll
            for (int rr = 0; rr < 4; ++rr) {
                int m = blockIdx.x * 128 + wm * 64 + mi * 16 + r0 + rr;
                float v = acc[mi][ni][rr];
                if (n < CHID) {
                    v += b1[n];
                    v = fmaxf(v, 0.0f);
                    hbuf[(size_t)m * CHID + n] = f2bf(v);
                } else {
                    int n2 = n - CHID;
                    resbuf[(size_t)m * COUT + n2] = v + bs[n2];
                }
            }
        }
}

// ---------------------------------------------------------------------------
// K4: GEMM2  hbuf[65536x256](bf16) @ W2[256x128] + b2 + resbuf -> relu -> out
// Same pipeline structure, K=256 (8 steps).
// ---------------------------------------------------------------------------
__global__ __launch_bounds__(256) void gemm2_kernel(
    const unsigned short* __restrict__ A, const unsigned short* __restrict__ Bt,
    const float* __restrict__ b2, const float* __restrict__ resbuf,
    float* __restrict__ out) {
    __shared__ unsigned short Alds[2][128 * 32];
    __shared__ unsigned short Blds[2][128 * 32];
    int tid = threadIdx.x;
    int wid = tid >> 6, lane = tid & 63;
    int widu = __builtin_amdgcn_readfirstlane(wid);
    int wm = wid >> 1, wn = wid & 1;
    int r = lane & 15, g = lane >> 4;
    int kcol = (g * 8) ^ (((r >> 1) & 3) * 8);

    const unsigned short* ga = A + (size_t)(blockIdx.x * 128) * CHID;

    f32x4 acc[4][4] = {};

    stage_ab(ga, CHID, Bt, CHID, Alds[0], Blds[0], 0, widu, lane);
    __syncthreads();
    int cur = 0;
#pragma unroll 1
    for (int t = 0; t < 8; ++t) {
        if (t + 1 < 8)
            stage_ab(ga, CHID, Bt, CHID, Alds[cur ^ 1], Blds[cur ^ 1],
                     (t + 1) * 32, widu, lane);
        bf16x8 af[4], bf[4];
#pragma unroll
        for (int mi = 0; mi < 4; ++mi)
            af[mi] = *(const bf16x8*)(&Alds[cur][(wm * 64 + mi * 16 + r) * 32 + kcol]);
#pragma unroll
        for (int ni = 0; ni < 4; ++ni)
            bf[ni] = *(const bf16x8*)(&Blds[cur][(wn * 64 + ni * 16 + r) * 32 + kcol]);
#pragma unroll
        for (int mi = 0; mi < 4; ++mi)
#pragma unroll
            for (int ni = 0; ni < 4; ++ni)
                acc[mi][ni] = __builtin_amdgcn_mfma_f32_16x16x32_bf16(
                    af[mi], bf[ni], acc[mi][ni], 0, 0, 0);
        __syncthreads();
        cur ^= 1;
    }

    int r0 = g * 4;
#pragma unroll
    for (int mi = 0; mi < 4; ++mi)
#pragma unroll
        for (int ni = 0; ni < 4; ++ni) {
            int n = wn * 64 + ni * 16 + r;   // 0..127
#pragma unroll
            for (int rr = 0; rr < 4; ++rr) {
                int m = blockIdx.x * 128 + wm * 64 + mi * 16 + r0 + rr;
                float v = acc[mi][ni][rr] + b2[n] + resbuf[(size_t)m * COUT + n];
                out[(size_t)m * COUT + n] = fmaxf(v, 0.0f);
            }
        }
}

// ---------------------------------------------------------------------------
extern "C" void kernel_launch(void* const* d_in, const int* in_sizes, int n_in,
                              void* d_out, int out_size, void* d_ws, size_t ws_size,
                              hipStream_t stream) {
    const float* x_t   = (const float*)d_in[0];
    const float* pos_t = (const float*)d_in[1];
    const float* x_s   = (const float*)d_in[3];
    const float* pos_s = (const float*)d_in[4];
    const float* W1    = (const float*)d_in[6];
    const float* b1    = (const float*)d_in[7];
    const float* W2    = (const float*)d_in[8];
    const float* b2    = (const float*)d_in[9];
    const float* Ws    = (const float*)d_in[10];
    const float* bs    = (const float*)d_in[11];

    char* ws = (char*)d_ws;
    int*            knn_i  = (int*)           (ws + 0);           //  786,432
    float*          knn_d  = (float*)         (ws + 786432);      //  786,432
    unsigned short* Wct    = (unsigned short*)(ws + 1572864);     //  294,912
    unsigned short* W2t    = (unsigned short*)(ws + 1867776);     //   65,536
    unsigned short* comb   = (unsigned short*)(ws + 1933312);     // 50,331,648
    unsigned short* hbuf   = (unsigned short*)(ws + 52264960);    // 33,554,432
    float*          resbuf = (float*)         (ws + 85819392);    // 33,554,432
    float*          out    = (float*)d_out;

    prep_weights<<<704, 256, 0, stream>>>(W1, Ws, W2, Wct, W2t);
    knn_kernel<<<NTOT / 32, 256, 0, stream>>>(pos_t, pos_s, knn_i, knn_d);
    interp_kernel<<<(NTOT * 96) / 256, 256, 0, stream>>>(x_t, x_s, knn_i, knn_d, comb);
    dim3 g1(NTOT / 128, CIN / 128);
    gemm1_kernel<<<g1, 256, 0, stream>>>(comb, Wct, b1, bs, hbuf, resbuf);
    gemm2_kernel<<<NTOT / 128, 256, 0, stream>>>(hbuf, W2t, b2, resbuf, out);
}

// Round 6
// 271.703 us; speedup vs baseline: 1.5773x; 1.0121x over previous
//
#include <hip/hip_runtime.h>
#include <hip/hip_bf16.h>

// Problem constants
#define B_    8
#define NT_   8192
#define NS_   2048
#define NTOT  (B_ * NT_)    // 65536 target points
#define CTGT  128
#define CSRC  256
#define CIN   384           // CTGT + CSRC
#define CHID  256
#define COUT  128

typedef __bf16 bf16x8 __attribute__((ext_vector_type(8)));
typedef float  f32x4  __attribute__((ext_vector_type(4)));
typedef unsigned short u16x8 __attribute__((ext_vector_type(8)));

__device__ inline unsigned short f2bf(float f) {
    unsigned int u = __float_as_uint(f);
    u += 0x7FFF + ((u >> 16) & 1);   // round-to-nearest-even
    return (unsigned short)(u >> 16);
}

// async global->LDS, 16B per lane, dest = wave-uniform base + lane*16
__device__ __forceinline__ void gload16(const unsigned short* g, unsigned short* l) {
    __builtin_amdgcn_global_load_lds(
        (const __attribute__((address_space(1))) unsigned int*)g,
        (__attribute__((address_space(3))) unsigned int*)l, 16, 0, 0);
}

// ---------------------------------------------------------------------------
// Shared GEMM staging: tile is [128 rows][32 cols] bf16, linear LDS (8KB).
// Swizzle (both-sides, rule #21): LDS[row][col] holds G[row][col ^ swz(row)],
// swz(row) = ((row>>1)&3)*8 elements. Staged via pre-swizzled global SOURCE
// (gload_lds dest must be linear); fragment reads apply the same XOR.
// ---------------------------------------------------------------------------
__device__ __forceinline__ void stage_ab(
    const unsigned short* __restrict__ ga, int ldA,
    const unsigned short* __restrict__ gb, int ldB,
    unsigned short* Alds, unsigned short* Blds,
    int k0, int widu, int lane) {
    int rloc = lane >> 2;                              // row within 16-row chunk
    int cswz = ((lane & 3) ^ ((lane >> 3) & 3)) * 8;   // pre-swizzled src col (elems)
#pragma unroll
    for (int i = 0; i < 2; ++i) {
        int c = widu * 2 + i;                          // chunk 0..7 (16 rows each)
        int row = c * 16 + rloc;
        gload16(ga + (size_t)row * ldA + k0 + cswz, Alds + c * 512);
        gload16(gb + (size_t)row * ldB + k0 + cswz, Blds + c * 512);
    }
}

// ---------------------------------------------------------------------------
// K0: build bf16 transposed weight matrices in workspace.
// ---------------------------------------------------------------------------
__global__ __launch_bounds__(256) void prep_weights(
    const float* __restrict__ W1, const float* __restrict__ Ws,
    const float* __restrict__ W2,
    unsigned short* __restrict__ Wct, unsigned short* __restrict__ W2t) {
    int g = blockIdx.x * 256 + threadIdx.x;
    if (g < CIN * CIN) {
        int n = g / CIN, k = g % CIN;
        float v = (n < CHID) ? W1[(size_t)k * CHID + n]
                             : Ws[(size_t)k * COUT + (n - CHID)];
        Wct[g] = f2bf(v);
    } else {
        int g2 = g - CIN * CIN;
        if (g2 < COUT * CHID) {
            int n = g2 / CHID, k = g2 % CHID;
            W2t[g2] = f2bf(W2[(size_t)k * COUT + n]);
        }
    }
}

// ---------------------------------------------------------------------------
// K1: brute-force KNN, 2 targets per thread.
// Block = 256 threads = 32 target-lanes x 8 source-chunks; each thread owns
// targets (tl, tl+32) -> block covers 64 targets. Grid = 1024 = 4 blocks/CU.
// ps4[j] loaded ONCE per thread serves both targets (amortizes ds_read +
// loop overhead; two independent update chains give ILP).
// Merge scratch REUSES ps4's LDS after a barrier -> 32 KB total.
// Selection arithmetic identical to validated round-3 kernel (no FMA,
// strict <, chunk-ascending merge preserves lowest-index tie-break).
// ---------------------------------------------------------------------------
__global__ __launch_bounds__(256) void knn_kernel(
    const float* __restrict__ pos_t, const float* __restrict__ pos_s,
    int* __restrict__ knn_i, float* __restrict__ knn_d) {
    __shared__ char smem[32768];
    float4* ps4 = (float4*)smem;                 // phase 1: 2048 x 16B = 32 KB
    float*  md  = (float*)smem;                  // phase 2: 64*8*3 floats = 6 KB
    int*    mi  = (int*)(smem + 6144);           // phase 2: 6 KB

    int blk = blockIdx.x;                        // 1024 blocks
    int batch = blk >> 7;                        // 128 blocks per batch
    const float* src = pos_s + (size_t)batch * NS_ * 3;
    for (int i = threadIdx.x; i < NS_; i += 256) {
        ps4[i] = make_float4(src[i * 3 + 0], src[i * 3 + 1], src[i * 3 + 2], 0.0f);
    }
    __syncthreads();

    int tl = threadIdx.x & 31;
    int ck = threadIdx.x >> 5;                   // chunk 0..7
    int tA = blk * 64 + tl;
    int tB = tA + 32;
    float ax = pos_t[tA * 3 + 0], ay = pos_t[tA * 3 + 1], az = pos_t[tA * 3 + 2];
    float bx = pos_t[tB * 3 + 0], by = pos_t[tB * 3 + 1], bz = pos_t[tB * 3 + 2];

    float a0 = 3.4e38f, a1 = 3.4e38f, a2 = 3.4e38f;
    float b0 = 3.4e38f, b1 = 3.4e38f, b2 = 3.4e38f;
    int ia0 = 0, ia1 = 0, ia2 = 0, ib0 = 0, ib1 = 0, ib2 = 0;
    int jbeg = ck * 256, jend = jbeg + 256;
#pragma unroll 2
    for (int j = jbeg; j < jend; ++j) {
        float4 p = ps4[j];
        float dax = __fsub_rn(ax, p.x);
        float day = __fsub_rn(ay, p.y);
        float daz = __fsub_rn(az, p.z);
        float da = __fadd_rn(__fadd_rn(__fmul_rn(dax, dax), __fmul_rn(day, day)),
                             __fmul_rn(daz, daz));
        float dbx = __fsub_rn(bx, p.x);
        float dby = __fsub_rn(by, p.y);
        float dbz = __fsub_rn(bz, p.z);
        float db = __fadd_rn(__fadd_rn(__fmul_rn(dbx, dbx), __fmul_rn(dby, dby)),
                             __fmul_rn(dbz, dbz));
        if (da < a2) {
            if (da < a1) {
                a2 = a1; ia2 = ia1;
                if (da < a0) { a1 = a0; ia1 = ia0; a0 = da; ia0 = j; }
                else         { a1 = da; ia1 = j; }
            } else { a2 = da; ia2 = j; }
        }
        if (db < b2) {
            if (db < b1) {
                b2 = b1; ib2 = ib1;
                if (db < b0) { b1 = b0; ib1 = ib0; b0 = db; ib0 = j; }
                else         { b1 = db; ib1 = j; }
            } else { b2 = db; ib2 = j; }
        }
    }
    __syncthreads();   // all ps4 reads done before overwriting with md/mi

    int sA = (tl * 8 + ck) * 3;          // [target][chunk][3]
    int sB = ((tl + 32) * 8 + ck) * 3;
    md[sA + 0] = a0; md[sA + 1] = a1; md[sA + 2] = a2;
    mi[sA + 0] = ia0; mi[sA + 1] = ia1; mi[sA + 2] = ia2;
    md[sB + 0] = b0; md[sB + 1] = b1; md[sB + 2] = b2;
    mi[sB + 0] = ib0; mi[sB + 1] = ib1; mi[sB + 2] = ib2;
    __syncthreads();

    if (threadIdx.x < 64) {
        int tloc = threadIdx.x;
        int t = blk * 64 + tloc;
        int base = tloc * 24;
        float e0 = md[base + 0], e1 = md[base + 1], e2 = md[base + 2];
        int   j0 = mi[base + 0], j1 = mi[base + 1], j2 = mi[base + 2];
#pragma unroll
        for (int c = 1; c < 8; ++c) {
#pragma unroll
            for (int r = 0; r < 3; ++r) {
                float d = md[base + c * 3 + r];
                int   i = mi[base + c * 3 + r];
                if (d < e2) {
                    if (d < e1) {
                        e2 = e1; j2 = j1;
                        if (d < e0) { e1 = e0; j1 = j0; e0 = d; j0 = i; }
                        else        { e1 = d;  j1 = i; }
                    } else { e2 = d; j2 = i; }
                }
            }
        }
        knn_i[t * 3 + 0] = j0; knn_i[t * 3 + 1] = j1; knn_i[t * 3 + 2] = j2;
        knn_d[t * 3 + 0] = e0; knn_d[t * 3 + 1] = e1; knn_d[t * 3 + 2] = e2;
    }
}

// ---------------------------------------------------------------------------
// K2: interpolate + concat -> combined bf16 [NTOT][384]  (unchanged).
// ---------------------------------------------------------------------------
__global__ __launch_bounds__(256) void interp_kernel(
    const float* __restrict__ x_t, const float* __restrict__ x_s,
    const int* __restrict__ knn_i, const float* __restrict__ knn_d,
    unsigned short* __restrict__ combined) {
    int g = blockIdx.x * 256 + threadIdx.x;
    int row = g / 96, seg = g % 96;
    if (row >= NTOT) return;
    if (seg < 32) {
        float4 v = *(const float4*)(x_t + (size_t)row * CTGT + seg * 4);
        ushort4 o;
        o.x = f2bf(v.x); o.y = f2bf(v.y); o.z = f2bf(v.z); o.w = f2bf(v.w);
        *(ushort4*)(combined + (size_t)row * CIN + seg * 4) = o;
    } else {
        int c = (seg - 32) * 4;
        int batch = row >> 13;
        const float* xsb = x_s + (size_t)batch * NS_ * CSRC;
        int i0 = knn_i[row * 3 + 0];
        int i1 = knn_i[row * 3 + 1];
        int i2 = knn_i[row * 3 + 2];
        float w0 = 1.0f / fmaxf(knn_d[row * 3 + 0], 1e-16f);
        float w1 = 1.0f / fmaxf(knn_d[row * 3 + 1], 1e-16f);
        float w2 = 1.0f / fmaxf(knn_d[row * 3 + 2], 1e-16f);
        float inv = 1.0f / (w0 + w1 + w2);
        float4 a = *(const float4*)(xsb + (size_t)i0 * CSRC + c);
        float4 b = *(const float4*)(xsb + (size_t)i1 * CSRC + c);
        float4 d = *(const float4*)(xsb + (size_t)i2 * CSRC + c);
        ushort4 o;
        o.x = f2bf((w0 * a.x + w1 * b.x + w2 * d.x) * inv);
        o.y = f2bf((w0 * a.y + w1 * b.y + w2 * d.y) * inv);
        o.z = f2bf((w0 * a.z + w1 * b.z + w2 * d.z) * inv);
        o.w = f2bf((w0 * a.w + w1 * b.w + w2 * d.w) * inv);
        *(ushort4*)(combined + (size_t)row * CIN + CTGT + c) = o;
    }
}

// ---------------------------------------------------------------------------
// K3: GEMM1  combined[65536x384](bf16) @ Wc[384x384], m97-style pipeline
// (unchanged from validated round 5).
// ---------------------------------------------------------------------------
__global__ __launch_bounds__(256) void gemm1_kernel(
    const unsigned short* __restrict__ A, const unsigned short* __restrict__ Bt,
    const float* __restrict__ b1, const float* __restrict__ bs,
    unsigned short* __restrict__ hbuf, float* __restrict__ resbuf) {
    __shared__ unsigned short Alds[2][128 * 32];
    __shared__ unsigned short Blds[2][128 * 32];
    int tid = threadIdx.x;
    int wid = tid >> 6, lane = tid & 63;
    int widu = __builtin_amdgcn_readfirstlane(wid);
    int wm = wid >> 1, wn = wid & 1;
    int r = lane & 15, g = lane >> 4;
    int kcol = (g * 8) ^ (((r >> 1) & 3) * 8);   // swizzled frag column (elems)

    const unsigned short* ga = A  + (size_t)(blockIdx.x * 128) * CIN;
    const unsigned short* gb = Bt + (size_t)(blockIdx.y * 128) * CIN;

    f32x4 acc[4][4] = {};

    stage_ab(ga, CIN, gb, CIN, Alds[0], Blds[0], 0, widu, lane);
    __syncthreads();
    int cur = 0;
#pragma unroll 1
    for (int t = 0; t < 12; ++t) {
        if (t + 1 < 12)
            stage_ab(ga, CIN, gb, CIN, Alds[cur ^ 1], Blds[cur ^ 1],
                     (t + 1) * 32, widu, lane);
        bf16x8 af[4], bf[4];
#pragma unroll
        for (int mi = 0; mi < 4; ++mi)
            af[mi] = *(const bf16x8*)(&Alds[cur][(wm * 64 + mi * 16 + r) * 32 + kcol]);
#pragma unroll
        for (int ni = 0; ni < 4; ++ni)
            bf[ni] = *(const bf16x8*)(&Blds[cur][(wn * 64 + ni * 16 + r) * 32 + kcol]);
#pragma unroll
        for (int mi = 0; mi < 4; ++mi)
#pragma unroll
            for (int ni = 0; ni < 4; ++ni)
                acc[mi][ni] = __builtin_amdgcn_mfma_f32_16x16x32_bf16(
                    af[mi], bf[ni], acc[mi][ni], 0, 0, 0);
        __syncthreads();   // drains prefetch vmcnt; frees buf[cur] for overwrite
        cur ^= 1;
    }

    int r0 = g * 4;
#pragma unroll
    for (int mi = 0; mi < 4; ++mi)
#pragma unroll
        for (int ni = 0; ni < 4; ++ni) {
            int n = blockIdx.y * 128 + wn * 64 + ni * 16 + r;
#pragma unroll
            for (int rr = 0; rr < 4; ++rr) {
                int m = blockIdx.x * 128 + wm * 64 + mi * 16 + r0 + rr;
                float v = acc[mi][ni][rr];
                if (n < CHID) {
                    v += b1[n];
                    v = fmaxf(v, 0.0f);
                    hbuf[(size_t)m * CHID + n] = f2bf(v);
                } else {
                    int n2 = n - CHID;
                    resbuf[(size_t)m * COUT + n2] = v + bs[n2];
                }
            }
        }
}

// ---------------------------------------------------------------------------
// K4: GEMM2  hbuf[65536x256](bf16) @ W2[256x128] + b2 + resbuf -> relu -> out
// (unchanged from validated round 5).
// ---------------------------------------------------------------------------
__global__ __launch_bounds__(256) void gemm2_kernel(
    const unsigned short* __restrict__ A, const unsigned short* __restrict__ Bt,
    const float* __restrict__ b2, const float* __restrict__ resbuf,
    float* __restrict__ out) {
    __shared__ unsigned short Alds[2][128 * 32];
    __shared__ unsigned short Blds[2][128 * 32];
    int tid = threadIdx.x;
    int wid = tid >> 6, lane = tid & 63;
    int widu = __builtin_amdgcn_readfirstlane(wid);
    int wm = wid >> 1, wn = wid & 1;
    int r = lane & 15, g = lane >> 4;
    int kcol = (g * 8) ^ (((r >> 1) & 3) * 8);

    const unsigned short* ga = A + (size_t)(blockIdx.x * 128) * CHID;

    f32x4 acc[4][4] = {};

    stage_ab(ga, CHID, Bt, CHID, Alds[0], Blds[0], 0, widu, lane);
    __syncthreads();
    int cur = 0;
#pragma unroll 1
    for (int t = 0; t < 8; ++t) {
        if (t + 1 < 8)
            stage_ab(ga, CHID, Bt, CHID, Alds[cur ^ 1], Blds[cur ^ 1],
                     (t + 1) * 32, widu, lane);
        bf16x8 af[4], bf[4];
#pragma unroll
        for (int mi = 0; mi < 4; ++mi)
            af[mi] = *(const bf16x8*)(&Alds[cur][(wm * 64 + mi * 16 + r) * 32 + kcol]);
#pragma unroll
        for (int ni = 0; ni < 4; ++ni)
            bf[ni] = *(const bf16x8*)(&Blds[cur][(wn * 64 + ni * 16 + r) * 32 + kcol]);
#pragma unroll
        for (int mi = 0; mi < 4; ++mi)
#pragma unroll
            for (int ni = 0; ni < 4; ++ni)
                acc[mi][ni] = __builtin_amdgcn_mfma_f32_16x16x32_bf16(
                    af[mi], bf[ni], acc[mi][ni], 0, 0, 0);
        __syncthreads();
        cur ^= 1;
    }

    int r0 = g * 4;
#pragma unroll
    for (int mi = 0; mi < 4; ++mi)
#pragma unroll
        for (int ni = 0; ni < 4; ++ni) {
            int n = wn * 64 + ni * 16 + r;   // 0..127
#pragma unroll
            for (int rr = 0; rr < 4; ++rr) {
                int m = blockIdx.x * 128 + wm * 64 + mi * 16 + r0 + rr;
                float v = acc[mi][ni][rr] + b2[n] + resbuf[(size_t)m * COUT + n];
                out[(size_t)m * COUT + n] = fmaxf(v, 0.0f);
            }
        }
}

// ---------------------------------------------------------------------------
extern "C" void kernel_launch(void* const* d_in, const int* in_sizes, int n_in,
                              void* d_out, int out_size, void* d_ws, size_t ws_size,
                              hipStream_t stream) {
    const float* x_t   = (const float*)d_in[0];
    const float* pos_t = (const float*)d_in[1];
    const float* x_s   = (const float*)d_in[3];
    const float* pos_s = (const float*)d_in[4];
    const float* W1    = (const float*)d_in[6];
    const float* b1    = (const float*)d_in[7];
    const float* W2    = (const float*)d_in[8];
    const float* b2    = (const float*)d_in[9];
    const float* Ws    = (const float*)d_in[10];
    const float* bs    = (const float*)d_in[11];

    char* ws = (char*)d_ws;
    int*            knn_i  = (int*)           (ws + 0);           //  786,432
    float*          knn_d  = (float*)         (ws + 786432);      //  786,432
    unsigned short* Wct    = (unsigned short*)(ws + 1572864);     //  294,912
    unsigned short* W2t    = (unsigned short*)(ws + 1867776);     //   65,536
    unsigned short* comb   = (unsigned short*)(ws + 1933312);     // 50,331,648
    unsigned short* hbuf   = (unsigned short*)(ws + 52264960);    // 33,554,432
    float*          resbuf = (float*)         (ws + 85819392);    // 33,554,432
    float*          out    = (float*)d_out;

    prep_weights<<<704, 256, 0, stream>>>(W1, Ws, W2, Wct, W2t);
    knn_kernel<<<NTOT / 64, 256, 0, stream>>>(pos_t, pos_s, knn_i, knn_d);
    interp_kernel<<<(NTOT * 96) / 256, 256, 0, stream>>>(x_t, x_s, knn_i, knn_d, comb);
    dim3 g1(NTOT / 128, CIN / 128);
    gemm1_kernel<<<g1, 256, 0, stream>>>(comb, Wct, b1, bs, hbuf, resbuf);
    gemm2_kernel<<<NTOT / 128, 256, 0, stream>>>(hbuf, W2t, b2, resbuf, out);
}

// Round 9
// 261.925 us; speedup vs baseline: 1.6362x; 1.0373x over previous
//
#include <hip/hip_runtime.h>
#include <hip/hip_bf16.h>

// Problem constants
#define B_    8
#define NT_   8192
#define NS_   2048
#define NTOT  (B_ * NT_)    // 65536 target points
#define CTGT  128
#define CSRC  256
#define CIN   384           // CTGT + CSRC
#define CHID  256
#define COUT  128

typedef __bf16 bf16x8 __attribute__((ext_vector_type(8)));
typedef float  f32x4  __attribute__((ext_vector_type(4)));
typedef unsigned short u16x8 __attribute__((ext_vector_type(8)));

__device__ inline unsigned short f2bf(float f) {
    unsigned int u = __float_as_uint(f);
    u += 0x7FFF + ((u >> 16) & 1);   // round-to-nearest-even
    return (unsigned short)(u >> 16);
}

// async global->LDS, 16B per lane, dest = wave-uniform base + lane*16
__device__ __forceinline__ void gload16(const unsigned short* g, unsigned short* l) {
    __builtin_amdgcn_global_load_lds(
        (const __attribute__((address_space(1))) unsigned int*)g,
        (__attribute__((address_space(3))) unsigned int*)l, 16, 0, 0);
}

// ---------------------------------------------------------------------------
// Shared GEMM staging: tile is [128 rows][32 cols] bf16, linear LDS (8KB).
// Swizzle (both-sides, rule #21): LDS[row][col] holds G[row][col ^ swz(row)],
// swz(row) = ((row>>1)&3)*8 elements. Staged via pre-swizzled global SOURCE
// (gload_lds dest must be linear); fragment reads apply the same XOR.
// ---------------------------------------------------------------------------
__device__ __forceinline__ void stage_ab(
    const unsigned short* __restrict__ ga, int ldA,
    const unsigned short* __restrict__ gb, int ldB,
    unsigned short* Alds, unsigned short* Blds,
    int k0, int widu, int lane) {
    int rloc = lane >> 2;                              // row within 16-row chunk
    int cswz = ((lane & 3) ^ ((lane >> 3) & 3)) * 8;   // pre-swizzled src col (elems)
#pragma unroll
    for (int i = 0; i < 2; ++i) {
        int c = widu * 2 + i;                          // chunk 0..7 (16 rows each)
        int row = c * 16 + rloc;
        gload16(ga + (size_t)row * ldA + k0 + cswz, Alds + c * 512);
        gload16(gb + (size_t)row * ldB + k0 + cswz, Blds + c * 512);
    }
}

// ---------------------------------------------------------------------------
// K0: build bf16 transposed weight matrices in workspace.
// ---------------------------------------------------------------------------
__global__ __launch_bounds__(256) void prep_weights(
    const float* __restrict__ W1, const float* __restrict__ Ws,
    const float* __restrict__ W2,
    unsigned short* __restrict__ Wct, unsigned short* __restrict__ W2t) {
    int g = blockIdx.x * 256 + threadIdx.x;
    if (g < CIN * CIN) {
        int n = g / CIN, k = g % CIN;
        float v = (n < CHID) ? W1[(size_t)k * CHID + n]
                             : Ws[(size_t)k * COUT + (n - CHID)];
        Wct[g] = f2bf(v);
    } else {
        int g2 = g - CIN * CIN;
        if (g2 < COUT * CHID) {
            int n = g2 / CHID, k = g2 % CHID;
            W2t[g2] = f2bf(W2[(size_t)k * COUT + n]);
        }
    }
}

// ---------------------------------------------------------------------------
// K1: brute-force KNN, 2 targets per thread, BRANCHLESS top-3 insert.
// Values: fminf + 2x v_med3_f32 (med3(d,a0,a1) == sorted-insert middle).
// Indices: 5 cndmask ternaries off the same three strict-< compares.
// Selection semantics identical to the validated cascade (strict <, ascending
// j, chunk-ascending merge) -> same neighbors, same tie-break.
// ---------------------------------------------------------------------------
__global__ __launch_bounds__(256) void knn_kernel(
    const float* __restrict__ pos_t, const float* __restrict__ pos_s,
    int* __restrict__ knn_i, float* __restrict__ knn_d) {
    __shared__ char smem[32768];
    float4* ps4 = (float4*)smem;                 // phase 1: 2048 x 16B = 32 KB
    float*  md  = (float*)smem;                  // phase 2: 64*8*3 floats = 6 KB
    int*    mi  = (int*)(smem + 6144);           // phase 2: 6 KB

    int blk = blockIdx.x;                        // 1024 blocks
    int batch = blk >> 7;                        // 128 blocks per batch
    const float* src = pos_s + (size_t)batch * NS_ * 3;
    for (int i = threadIdx.x; i < NS_; i += 256) {
        ps4[i] = make_float4(src[i * 3 + 0], src[i * 3 + 1], src[i * 3 + 2], 0.0f);
    }
    __syncthreads();

    int tl = threadIdx.x & 31;
    int ck = threadIdx.x >> 5;                   // chunk 0..7
    int tA = blk * 64 + tl;
    int tB = tA + 32;
    float ax = pos_t[tA * 3 + 0], ay = pos_t[tA * 3 + 1], az = pos_t[tA * 3 + 2];
    float bx = pos_t[tB * 3 + 0], by = pos_t[tB * 3 + 1], bz = pos_t[tB * 3 + 2];

    float a0 = 3.4e38f, a1 = 3.4e38f, a2 = 3.4e38f;
    float b0 = 3.4e38f, b1 = 3.4e38f, b2 = 3.4e38f;
    int ia0 = 0, ia1 = 0, ia2 = 0, ib0 = 0, ib1 = 0, ib2 = 0;
    int jbeg = ck * 256, jend = jbeg + 256;
#pragma unroll 4
    for (int j = jbeg; j < jend; ++j) {
        float4 p = ps4[j];
        float dax = __fsub_rn(ax, p.x);
        float day = __fsub_rn(ay, p.y);
        float daz = __fsub_rn(az, p.z);
        float da = __fadd_rn(__fadd_rn(__fmul_rn(dax, dax), __fmul_rn(day, day)),
                             __fmul_rn(daz, daz));
        float dbx = __fsub_rn(bx, p.x);
        float dby = __fsub_rn(by, p.y);
        float dbz = __fsub_rn(bz, p.z);
        float db = __fadd_rn(__fadd_rn(__fmul_rn(dbx, dbx), __fmul_rn(dby, dby)),
                             __fmul_rn(dbz, dbz));
        // target A: branchless sorted insert of (da, j)
        {
            bool c0 = da < a0, c1 = da < a1, c2 = da < a2;
            int ni2 = c2 ? (c1 ? ia1 : j) : ia2;
            int ni1 = c1 ? (c0 ? ia0 : j) : ia1;
            int ni0 = c0 ? j : ia0;
            float na2 = __builtin_amdgcn_fmed3f(da, a1, a2);
            float na1 = __builtin_amdgcn_fmed3f(da, a0, a1);
            float na0 = fminf(a0, da);
            a0 = na0; a1 = na1; a2 = na2;
            ia0 = ni0; ia1 = ni1; ia2 = ni2;
        }
        // target B
        {
            bool c0 = db < b0, c1 = db < b1, c2 = db < b2;
            int ni2 = c2 ? (c1 ? ib1 : j) : ib2;
            int ni1 = c1 ? (c0 ? ib0 : j) : ib1;
            int ni0 = c0 ? j : ib0;
            float nb2 = __builtin_amdgcn_fmed3f(db, b1, b2);
            float nb1 = __builtin_amdgcn_fmed3f(db, b0, b1);
            float nb0 = fminf(b0, db);
            b0 = nb0; b1 = nb1; b2 = nb2;
            ib0 = ni0; ib1 = ni1; ib2 = ni2;
        }
    }
    __syncthreads();   // all ps4 reads done before overwriting with md/mi

    int sA = (tl * 8 + ck) * 3;          // [target][chunk][3]
    int sB = ((tl + 32) * 8 + ck) * 3;
    md[sA + 0] = a0; md[sA + 1] = a1; md[sA + 2] = a2;
    mi[sA + 0] = ia0; mi[sA + 1] = ia1; mi[sA + 2] = ia2;
    md[sB + 0] = b0; md[sB + 1] = b1; md[sB + 2] = b2;
    mi[sB + 0] = ib0; mi[sB + 1] = ib1; mi[sB + 2] = ib2;
    __syncthreads();

    if (threadIdx.x < 64) {
        int tloc = threadIdx.x;
        int t = blk * 64 + tloc;
        int base = tloc * 24;
        float e0 = md[base + 0], e1 = md[base + 1], e2 = md[base + 2];
        int   j0 = mi[base + 0], j1 = mi[base + 1], j2 = mi[base + 2];
#pragma unroll
        for (int c = 1; c < 8; ++c) {
#pragma unroll
            for (int r = 0; r < 3; ++r) {
                float d = md[base + c * 3 + r];
                int   i = mi[base + c * 3 + r];
                bool c0 = d < e0, c1 = d < e1, c2 = d < e2;
                int nj2 = c2 ? (c1 ? j1 : i) : j2;
                int nj1 = c1 ? (c0 ? j0 : i) : j1;
                int nj0 = c0 ? i : j0;
                float ne2 = __builtin_amdgcn_fmed3f(d, e1, e2);
                float ne1 = __builtin_amdgcn_fmed3f(d, e0, e1);
                float ne0 = fminf(e0, d);
                e0 = ne0; e1 = ne1; e2 = ne2;
                j0 = nj0; j1 = nj1; j2 = nj2;
            }
        }
        knn_i[t * 3 + 0] = j0; knn_i[t * 3 + 1] = j1; knn_i[t * 3 + 2] = j2;
        knn_d[t * 3 + 0] = e0; knn_d[t * 3 + 1] = e1; knn_d[t * 3 + 2] = e2;
    }
}

// ---------------------------------------------------------------------------
// K2: interpolate + concat -> combined bf16 [NTOT][384]  (unchanged).
// ---------------------------------------------------------------------------
__global__ __launch_bounds__(256) void interp_kernel(
    const float* __restrict__ x_t, const float* __restrict__ x_s,
    const int* __restrict__ knn_i, const float* __restrict__ knn_d,
    unsigned short* __restrict__ combined) {
    int g = blockIdx.x * 256 + threadIdx.x;
    int row = g / 96, seg = g % 96;
    if (row >= NTOT) return;
    if (seg < 32) {
        float4 v = *(const float4*)(x_t + (size_t)row * CTGT + seg * 4);
        ushort4 o;
        o.x = f2bf(v.x); o.y = f2bf(v.y); o.z = f2bf(v.z); o.w = f2bf(v.w);
        *(ushort4*)(combined + (size_t)row * CIN + seg * 4) = o;
    } else {
        int c = (seg - 32) * 4;
        int batch = row >> 13;
        const float* xsb = x_s + (size_t)batch * NS_ * CSRC;
        int i0 = knn_i[row * 3 + 0];
        int i1 = knn_i[row * 3 + 1];
        int i2 = knn_i[row * 3 + 2];
        float w0 = 1.0f / fmaxf(knn_d[row * 3 + 0], 1e-16f);
        float w1 = 1.0f / fmaxf(knn_d[row * 3 + 1], 1e-16f);
        float w2 = 1.0f / fmaxf(knn_d[row * 3 + 2], 1e-16f);
        float inv = 1.0f / (w0 + w1 + w2);
        float4 a = *(const float4*)(xsb + (size_t)i0 * CSRC + c);
        float4 b = *(const float4*)(xsb + (size_t)i1 * CSRC + c);
        float4 d = *(const float4*)(xsb + (size_t)i2 * CSRC + c);
        ushort4 o;
        o.x = f2bf((w0 * a.x + w1 * b.x + w2 * d.x) * inv);
        o.y = f2bf((w0 * a.y + w1 * b.y + w2 * d.y) * inv);
        o.z = f2bf((w0 * a.z + w1 * b.z + w2 * d.z) * inv);
        o.w = f2bf((w0 * a.w + w1 * b.w + w2 * d.w) * inv);
        *(ushort4*)(combined + (size_t)row * CIN + CTGT + c) = o;
    }
}

// ---------------------------------------------------------------------------
// K3: GEMM1  combined[65536x384](bf16) @ Wc[384x384], m97-style pipeline.
// T1 XCD swizzle (bijective, 1536 = 8*192): sid = (id&7)*192 + id>>3,
// bn-fastest -> the 3 bn-siblings of each bm run on the SAME XCD, so the
// A-tile is fetched from HBM once and L2 serves the other two.
// ---------------------------------------------------------------------------
__global__ __launch_bounds__(256) void gemm1_kernel(
    const unsigned short* __restrict__ A, const unsigned short* __restrict__ Bt,
    const float* __restrict__ b1, const float* __restrict__ bs,
    unsigned short* __restrict__ hbuf, float* __restrict__ resbuf) {
    __shared__ unsigned short Alds[2][128 * 32];
    __shared__ unsigned short Blds[2][128 * 32];
    int id = blockIdx.x;                   // 0..1535
    int sid = (id & 7) * 192 + (id >> 3);  // XCD-chunked, bijective
    int bm = sid / 3, bn = sid - bm * 3;
    int tid = threadIdx.x;
    int wid = tid >> 6, lane = tid & 63;
    int widu = __builtin_amdgcn_readfirstlane(wid);
    int wm = wid >> 1, wn = wid & 1;
    int r = lane & 15, g = lane >> 4;
    int kcol = (g * 8) ^ (((r >> 1) & 3) * 8);   // swizzled frag column (elems)

    const unsigned short* ga = A  + (size_t)(bm * 128) * CIN;
    const unsigned short* gb = Bt + (size_t)(bn * 128) * CIN;

    f32x4 acc[4][4] = {};

    stage_ab(ga, CIN, gb, CIN, Alds[0], Blds[0], 0, widu, lane);
    __syncthreads();
    int cur = 0;
#pragma unroll 1
    for (int t = 0; t < 12; ++t) {
        if (t + 1 < 12)
            stage_ab(ga, CIN, gb, CIN, Alds[cur ^ 1], Blds[cur ^ 1],
                     (t + 1) * 32, widu, lane);
        bf16x8 af[4], bf[4];
#pragma unroll
        for (int mi = 0; mi < 4; ++mi)
            af[mi] = *(const bf16x8*)(&Alds[cur][(wm * 64 + mi * 16 + r) * 32 + kcol]);
#pragma unroll
        for (int ni = 0; ni < 4; ++ni)
            bf[ni] = *(const bf16x8*)(&Blds[cur][(wn * 64 + ni * 16 + r) * 32 + kcol]);
#pragma unroll
        for (int mi = 0; mi < 4; ++mi)
#pragma unroll
            for (int ni = 0; ni < 4; ++ni)
                acc[mi][ni] = __builtin_amdgcn_mfma_f32_16x16x32_bf16(
                    af[mi], bf[ni], acc[mi][ni], 0, 0, 0);
        __syncthreads();   // drains prefetch vmcnt; frees buf[cur] for overwrite
        cur ^= 1;
    }

    int r0 = g * 4;
#pragma unroll
    for (int mi = 0; mi < 4; ++mi)
#pragma unroll
        for (int ni = 0; ni < 4; ++ni) {
            int n = bn * 128 + wn * 64 + ni * 16 + r;
#pragma unroll
            for (int rr = 0; rr < 4; ++rr) {
                int m = bm * 128 + wm * 64 + mi * 16 + r0 + rr;
                float v = acc[mi][ni][rr];
                if (n < CHID) {
                    v += b1[n];
                    v = fmaxf(v, 0.0f);
                    hbuf[(size_t)m * CHID + n] = f2bf(v);
                } else {
                    int n2 = n - CHID;
                    resbuf[(size_t)m * COUT + n2] = v + bs[n2];
                }
            }
        }
}

// ---------------------------------------------------------------------------
// K4: GEMM2  hbuf[65536x256](bf16) @ W2[256x128] + b2 + resbuf -> relu -> out
// (unchanged from validated round 5).
// ---------------------------------------------------------------------------
__global__ __launch_bounds__(256) void gemm2_kernel(
    const unsigned short* __restrict__ A, const unsigned short* __restrict__ Bt,
    const float* __restrict__ b2, const float* __restrict__ resbuf,
    float* __restrict__ out) {
    __shared__ unsigned short Alds[2][128 * 32];
    __shared__ unsigned short Blds[2][128 * 32];
    int tid = threadIdx.x;
    int wid = tid >> 6, lane = tid & 63;
    int widu = __builtin_amdgcn_readfirstlane(wid);
    int wm = wid >> 1, wn = wid & 1;
    int r = lane & 15, g = lane >> 4;
    int kcol = (g * 8) ^ (((r >> 1) & 3) * 8);

    const unsigned short* ga = A + (size_t)(blockIdx.x * 128) * CHID;

    f32x4 acc[4][4] = {};

    stage_ab(ga, CHID, Bt, CHID, Alds[0], Blds[0], 0, widu, lane);
    __syncthreads();
    int cur = 0;
#pragma unroll 1
    for (int t = 0; t < 8; ++t) {
        if (t + 1 < 8)
            stage_ab(ga, CHID, Bt, CHID, Alds[cur ^ 1], Blds[cur ^ 1],
                     (t + 1) * 32, widu, lane);
        bf16x8 af[4], bf[4];
#pragma unroll
        for (int mi = 0; mi < 4; ++mi)
            af[mi] = *(const bf16x8*)(&Alds[cur][(wm * 64 + mi * 16 + r) * 32 + kcol]);
#pragma unroll
        for (int ni = 0; ni < 4; ++ni)
            bf[ni] = *(const bf16x8*)(&Blds[cur][(wn * 64 + ni * 16 + r) * 32 + kcol]);
#pragma unroll
        for (int mi = 0; mi < 4; ++mi)
#pragma unroll
            for (int ni = 0; ni < 4; ++ni)
                acc[mi][ni] = __builtin_amdgcn_mfma_f32_16x16x32_bf16(
                    af[mi], bf[ni], acc[mi][ni], 0, 0, 0);
        __syncthreads();
        cur ^= 1;
    }

    int r0 = g * 4;
#pragma unroll
    for (int mi = 0; mi < 4; ++mi)
#pragma unroll
        for (int ni = 0; ni < 4; ++ni) {
            int n = wn * 64 + ni * 16 + r;   // 0..127
#pragma unroll
            for (int rr = 0; rr < 4; ++rr) {
                int m = blockIdx.x * 128 + wm * 64 + mi * 16 + r0 + rr;
                float v = acc[mi][ni][rr] + b2[n] + resbuf[(size_t)m * COUT + n];
                out[(size_t)m * COUT + n] = fmaxf(v, 0.0f);
            }
        }
}

// ---------------------------------------------------------------------------
extern "C" void kernel_launch(void* const* d_in, const int* in_sizes, int n_in,
                              void* d_out, int out_size, void* d_ws, size_t ws_size,
                              hipStream_t stream) {
    const float* x_t   = (const float*)d_in[0];
    const float* pos_t = (const float*)d_in[1];
    const float* x_s   = (const float*)d_in[3];
    const float* pos_s = (const float*)d_in[4];
    const float* W1    = (const float*)d_in[6];
    const float* b1    = (const float*)d_in[7];
    const float* W2    = (const float*)d_in[8];
    const float* b2    = (const float*)d_in[9];
    const float* Ws    = (const float*)d_in[10];
    const float* bs    = (const float*)d_in[11];

    char* ws = (char*)d_ws;
    int*            knn_i  = (int*)           (ws + 0);           //  786,432
    float*          knn_d  = (float*)         (ws + 786432);      //  786,432
    unsigned short* Wct    = (unsigned short*)(ws + 1572864);     //  294,912
    unsigned short* W2t    = (unsigned short*)(ws + 1867776);     //   65,536
    unsigned short* comb   = (unsigned short*)(ws + 1933312);     // 50,331,648
    unsigned short* hbuf   = (unsigned short*)(ws + 52264960);    // 33,554,432
    float*          resbuf = (float*)         (ws + 85819392);    // 33,554,432
    float*          out    = (float*)d_out;

    prep_weights<<<704, 256, 0, stream>>>(W1, Ws, W2, Wct, W2t);
    knn_kernel<<<NTOT / 64, 256, 0, stream>>>(pos_t, pos_s, knn_i, knn_d);
    interp_kernel<<<(NTOT * 96) / 256, 256, 0, stream>>>(x_t, x_s, knn_i, knn_d, comb);
    gemm1_kernel<<<1536, 256, 0, stream>>>(comb, Wct, b1, bs, hbuf, resbuf);
    gemm2_kernel<<<NTOT / 128, 256, 0, stream>>>(hbuf, W2t, b2, resbuf, out);
}